// Round 2
// baseline (533.605 us; speedup 1.0000x reference)
//
#include <hip/hip_runtime.h>
#include <math.h>

typedef float  f32x4 __attribute__((ext_vector_type(4)));
typedef short  s16x8 __attribute__((ext_vector_type(8)));
typedef unsigned short u16;
typedef unsigned int u32;

// ---------- bf16 helpers ----------
static __device__ __forceinline__ u16 f32_to_bf16_rne(float f) {
    u32 u = __builtin_bit_cast(u32, f);
    u32 r = u + 0x7fffu + ((u >> 16) & 1u);
    return (u16)(r >> 16);
}
static __device__ __forceinline__ u16 f32_to_bf16_rhu(float f) {  // round half up (cheap)
    u32 u = __builtin_bit_cast(u32, f);
    return (u16)((u + 0x8000u) >> 16);
}
static __device__ __forceinline__ float bf16_to_f32(u16 h) {
    return __builtin_bit_cast(float, (u32)h << 16);
}

// async global->LDS 16B: lds dest = wave-uniform base + lane*16
static __device__ __forceinline__ void gl2lds16(const void* g, void* l) {
    __builtin_amdgcn_global_load_lds(
        (const __attribute__((address_space(1))) u32*)g,
        (__attribute__((address_space(3))) u32*)l, 16, 0, 0);
}

// ---------- 1) cast fp32 -> bf16 ----------
__global__ void k_cast(const float* __restrict__ in, u16* __restrict__ out) {
    int i = (blockIdx.x * 256 + threadIdx.x) * 4;
    float4 v = *reinterpret_cast<const float4*>(in + i);
    ushort4 u;
    u.x = f32_to_bf16_rne(v.x); u.y = f32_to_bf16_rne(v.y);
    u.z = f32_to_bf16_rne(v.z); u.w = f32_to_bf16_rne(v.w);
    *reinterpret_cast<ushort4*>(out + i) = u;
}

// ---------- 2) transpose + cast: W (R x C fp32) -> Wt (C x R bf16) ----------
__global__ void k_transpose_cast(const float* __restrict__ in, u16* __restrict__ out,
                                 int R, int C) {
    __shared__ __align__(16) float tile[64 * 68];
    const int ct = blockIdx.x, rt = blockIdx.y;
    const int t = threadIdx.x;
    const int tr = t >> 4;
    const int tc4 = (t & 15) * 4;
#pragma unroll
    for (int rn = 0; rn < 4; ++rn) {
        int r = rn * 16 + tr;
        float4 v = *reinterpret_cast<const float4*>(in + (size_t)(rt * 64 + r) * C + ct * 64 + tc4);
        *reinterpret_cast<float4*>(&tile[r * 68 + tc4]) = v;
    }
    __syncthreads();
#pragma unroll
    for (int rn = 0; rn < 4; ++rn) {
        int oc = rn * 16 + tr;
        ushort4 u;
        u.x = f32_to_bf16_rne(tile[(tc4 + 0) * 68 + oc]);
        u.y = f32_to_bf16_rne(tile[(tc4 + 1) * 68 + oc]);
        u.z = f32_to_bf16_rne(tile[(tc4 + 2) * 68 + oc]);
        u.w = f32_to_bf16_rne(tile[(tc4 + 3) * 68 + oc]);
        *reinterpret_cast<ushort4*>(out + (size_t)(ct * 64 + oc) * R + rt * 64 + tc4) = u;
    }
}

// ---------- 3) GEMM m97-style: C[M,N] = A[M,K] * Bt[N,K]^T ----------
// BK=64, global_load_lds dwordx4 staging, XOR-swizzled LDS [128][64]:
// element (row, chunk c of 8 elems) stored at phys chunk p = c ^ (row&7).
// Row stride 128B == 0 mod 32 banks -> bank = phys chunk -> frag reads conflict-free.
template<bool BF16OUT>
__global__ __launch_bounds__(256) void k_gemm_bt(const u16* __restrict__ Amat,
                                                 const u16* __restrict__ Bt,
                                                 void* __restrict__ Cout,
                                                 int M, int N, int K) {
    __shared__ __align__(16) u16 As[128 * 64];
    __shared__ __align__(16) u16 Bs[128 * 64];
    const int t = threadIdx.x;
    const int lane = t & 63, wave = t >> 6;
    const int m16 = lane & 15, qd = lane >> 4;
    const int wm = (wave >> 1) * 64, wn = (wave & 1) * 64;
    const size_t m0 = (size_t)blockIdx.y * 128, n0 = (size_t)blockIdx.x * 128;
    const int srow = lane >> 3;                // 0..7 (row within wave's 8-row slab)
    const int schunk = (lane & 7) ^ srow;      // logical chunk this lane fetches

    f32x4 acc[4][4] = {};

    for (int k0 = 0; k0 < K; k0 += 64) {
#pragma unroll
        for (int j = 0; j < 4; ++j) {
            int rbase = j * 32 + wave * 8;
            int r = rbase + srow;
            gl2lds16(Amat + (m0 + r) * (size_t)K + k0 + schunk * 8, &As[rbase * 64]);
            gl2lds16(Bt   + (n0 + r) * (size_t)K + k0 + schunk * 8, &Bs[rbase * 64]);
        }
        __syncthreads();
#pragma unroll
        for (int kh = 0; kh < 2; ++kh) {
            s16x8 af[4], bf[4];
#pragma unroll
            for (int i = 0; i < 4; ++i) {
                int ra = wm + i * 16 + m16;
                int pa = (kh * 4 + qd) ^ (ra & 7);
                af[i] = *reinterpret_cast<const s16x8*>(&As[ra * 64 + pa * 8]);
                int rb = wn + i * 16 + m16;
                int pb = (kh * 4 + qd) ^ (rb & 7);
                bf[i] = *reinterpret_cast<const s16x8*>(&Bs[rb * 64 + pb * 8]);
            }
#pragma unroll
            for (int i = 0; i < 4; ++i)
#pragma unroll
                for (int jj = 0; jj < 4; ++jj)
                    acc[i][jj] = __builtin_amdgcn_mfma_f32_16x16x32_bf16(af[i], bf[jj], acc[i][jj], 0, 0, 0);
        }
        __syncthreads();
    }
    // C/D layout: col = lane&15, row = (lane>>4)*4 + reg
#pragma unroll
    for (int i = 0; i < 4; ++i)
#pragma unroll
        for (int j = 0; j < 4; ++j)
#pragma unroll
            for (int r = 0; r < 4; ++r) {
                size_t row = m0 + wm + i * 16 + qd * 4 + r;
                size_t col = n0 + wn + j * 16 + m16;
                if (BF16OUT)
                    ((u16*)Cout)[row * N + col] = f32_to_bf16_rne(acc[i][j][r]);
                else
                    ((float*)Cout)[row * N + col] = acc[i][j][r];
            }
}

// ---------- 4) RoPE in-place on q,k halves of qkv (bf16) ----------
__global__ void k_rope(u16* __restrict__ qkv) {
    int idx = blockIdx.x * 256 + threadIdx.x;
    int row = idx >> 11;
    int p = idx & 2047;
    int s = row & 2047;
    int which = p >> 10;
    int rem = p & 1023;
    int h = rem >> 6;
    int i = rem & 63;
    size_t off = (size_t)row * 6144 + (size_t)which * 2048 + h * 128 + 2 * i;
    u32 v = *reinterpret_cast<u32*>(qkv + off);
    float x1 = bf16_to_f32((u16)(v & 0xffffu));
    float x2 = bf16_to_f32((u16)(v >> 16));
    float inv = expf(-0.14391156831f * (float)i);
    float f = (float)s * inv;
    float cs = cosf(f), sn = sinf(f);
    float o1 = x1 * cs - x2 * sn;
    float o2 = x1 * sn + x2 * cs;
    u32 w = (u32)f32_to_bf16_rne(o1) | ((u32)f32_to_bf16_rne(o2) << 16);
    *reinterpret_cast<u32*>(qkv + off) = w;
}

// ---------- 5) V -> V^T ----------
__global__ void k_transpose_v(const u16* __restrict__ qkv, u16* __restrict__ vt) {
    __shared__ u16 tile[64 * 68];
    const int st = blockIdx.x;
    const int bhd = blockIdx.y;
    const int bh = bhd >> 1, dt = bhd & 1;
    const u16* src = qkv + (size_t)(bh >> 4) * 2048 * 6144 + 4096 + (size_t)(bh & 15) * 128 + dt * 64;
    const int t = threadIdx.x, tr = t >> 4, tc4 = (t & 15) * 4;
#pragma unroll
    for (int rn = 0; rn < 4; ++rn) {
        int s = rn * 16 + tr;
        *reinterpret_cast<ushort4*>(&tile[s * 68 + tc4]) =
            *reinterpret_cast<const ushort4*>(src + (size_t)(st * 64 + s) * 6144 + tc4);
    }
    __syncthreads();
    u16* dst = vt + ((size_t)bh * 128 + dt * 64) * 2048 + st * 64;
#pragma unroll
    for (int rn = 0; rn < 4; ++rn) {
        int d = rn * 16 + tr;
        ushort4 u;
        u.x = tile[(tc4 + 0) * 68 + d];
        u.y = tile[(tc4 + 1) * 68 + d];
        u.z = tile[(tc4 + 2) * 68 + d];
        u.w = tile[(tc4 + 3) * 68 + d];
        *reinterpret_cast<ushort4*>(dst + (size_t)d * 2048 + tc4) = u;
    }
}

// ---------- 6) flash attention with K/V register prefetch ----------
__global__ __launch_bounds__(256, 2) void k_flash(const u16* __restrict__ qkv,
                                                  const u16* __restrict__ vt,
                                                  u16* __restrict__ out) {
    __shared__ __align__(16) u16 KP[128 * 152];
    __shared__ __align__(16) u16 VT[128 * 152];
    const int t = threadIdx.x, lane = t & 63, wave = t >> 6;
    const int m16 = lane & 15, qd = lane >> 4;
    const int bh = blockIdx.y, b = bh >> 4, h = bh & 15;
    const int q0 = blockIdx.x * 128;
    const int wq = wave * 32;
    const u16* Qg = qkv + (size_t)b * 2048 * 6144 + (size_t)h * 128;
    const u16* Kg = Qg + 2048;
    const u16* Vtg = vt + (size_t)bh * 128 * 2048;
    const float C2 = 0.12751743f;   // (1/sqrt(128)) * log2(e)

    // Persistent Q fragments
    s16x8 qf[2][4];
#pragma unroll
    for (int mi = 0; mi < 2; ++mi)
#pragma unroll
        for (int kc = 0; kc < 4; ++kc)
            qf[mi][kc] = *reinterpret_cast<const s16x8*>(
                Qg + (size_t)(q0 + wq + mi * 16 + m16) * 6144 + kc * 32 + qd * 8);

    f32x4 accO[2][8] = {};
    float mrow[2][4], lrow[2][4];
#pragma unroll
    for (int mi = 0; mi < 2; ++mi)
#pragma unroll
        for (int r = 0; r < 4; ++r) { mrow[mi][r] = -1e30f; lrow[mi][r] = 0.f; }

    const int strow = t >> 4;        // 0..15
    const int stc = (t & 15) * 8;    // 0..120

    // preload tile 0 into registers
    s16x8 kreg[8], vreg[8];
#pragma unroll
    for (int rd = 0; rd < 8; ++rd) {
        int row = rd * 16 + strow;
        kreg[rd] = *reinterpret_cast<const s16x8*>(Kg + (size_t)row * 6144 + stc);
        vreg[rd] = *reinterpret_cast<const s16x8*>(Vtg + (size_t)row * 2048 + stc);
    }

    for (int kt = 0; kt < 16; ++kt) {
        __syncthreads();   // prev iter's LDS reads done (also drains prefetch vmcnt)
#pragma unroll
        for (int rd = 0; rd < 8; ++rd) {
            int row = rd * 16 + strow;
            *reinterpret_cast<s16x8*>(&KP[row * 152 + stc]) = kreg[rd];
            *reinterpret_cast<s16x8*>(&VT[row * 152 + stc]) = vreg[rd];
        }
        __syncthreads();

        // prefetch next tile into registers; latency overlaps QK^T+softmax+PV
        if (kt < 15) {
            const int s1 = (kt + 1) * 128;
#pragma unroll
            for (int rd = 0; rd < 8; ++rd) {
                int row = rd * 16 + strow;
                kreg[rd] = *reinterpret_cast<const s16x8*>(Kg + (size_t)(s1 + row) * 6144 + stc);
                vreg[rd] = *reinterpret_cast<const s16x8*>(Vtg + (size_t)row * 2048 + s1 + stc);
            }
        }

        // QK^T
        f32x4 accS[2][8] = {};
#pragma unroll
        for (int kc = 0; kc < 4; ++kc)
#pragma unroll
            for (int nj = 0; nj < 8; ++nj) {
                s16x8 kf = *reinterpret_cast<const s16x8*>(&KP[(nj * 16 + m16) * 152 + kc * 32 + qd * 8]);
                accS[0][nj] = __builtin_amdgcn_mfma_f32_16x16x32_bf16(qf[0][kc], kf, accS[0][nj], 0, 0, 0);
                accS[1][nj] = __builtin_amdgcn_mfma_f32_16x16x32_bf16(qf[1][kc], kf, accS[1][nj], 0, 0, 0);
            }
        __syncthreads();   // all K reads done before P overwrites KP

        // online softmax in exp2 domain
        float alpha[2][4], psum[2][4];
#pragma unroll
        for (int mi = 0; mi < 2; ++mi)
#pragma unroll
            for (int r = 0; r < 4; ++r) {
                float mx = accS[mi][0][r];
#pragma unroll
                for (int nj = 1; nj < 8; ++nj) mx = fmaxf(mx, accS[mi][nj][r]);
#pragma unroll
                for (int off = 1; off < 16; off <<= 1) mx = fmaxf(mx, __shfl_xor(mx, off));
                float mn = fmaxf(mrow[mi][r], mx * C2);
                alpha[mi][r] = exp2f(mrow[mi][r] - mn);
                mrow[mi][r] = mn;
                psum[mi][r] = 0.f;
            }
#pragma unroll
        for (int mi = 0; mi < 2; ++mi)
#pragma unroll
            for (int nj = 0; nj < 8; ++nj)
#pragma unroll
                for (int r = 0; r < 4; ++r) {
                    float p = exp2f(accS[mi][nj][r] * C2 - mrow[mi][r]);
                    psum[mi][r] += p;
                    KP[(wq + mi * 16 + qd * 4 + r) * 152 + nj * 16 + m16] = f32_to_bf16_rhu(p);
                }
#pragma unroll
        for (int mi = 0; mi < 2; ++mi)
#pragma unroll
            for (int r = 0; r < 4; ++r) {
                float sum = psum[mi][r];
#pragma unroll
                for (int off = 1; off < 16; off <<= 1) sum += __shfl_xor(sum, off);
                lrow[mi][r] = lrow[mi][r] * alpha[mi][r] + sum;
            }
#pragma unroll
        for (int mi = 0; mi < 2; ++mi)
#pragma unroll
            for (int dj = 0; dj < 8; ++dj)
#pragma unroll
                for (int r = 0; r < 4; ++r) accO[mi][dj][r] *= alpha[mi][r];

        // PV (reads own wave's P rows — no barrier needed)
#pragma unroll
        for (int ks = 0; ks < 4; ++ks) {
            s16x8 pf0 = *reinterpret_cast<const s16x8*>(&KP[(wq + m16) * 152 + ks * 32 + qd * 8]);
            s16x8 pf1 = *reinterpret_cast<const s16x8*>(&KP[(wq + 16 + m16) * 152 + ks * 32 + qd * 8]);
#pragma unroll
            for (int dj = 0; dj < 8; ++dj) {
                s16x8 vf = *reinterpret_cast<const s16x8*>(&VT[(dj * 16 + m16) * 152 + ks * 32 + qd * 8]);
                accO[0][dj] = __builtin_amdgcn_mfma_f32_16x16x32_bf16(pf0, vf, accO[0][dj], 0, 0, 0);
                accO[1][dj] = __builtin_amdgcn_mfma_f32_16x16x32_bf16(pf1, vf, accO[1][dj], 0, 0, 0);
            }
        }
    }
    // epilogue
#pragma unroll
    for (int mi = 0; mi < 2; ++mi)
#pragma unroll
        for (int r = 0; r < 4; ++r) {
            float inv = 1.0f / lrow[mi][r];
            size_t row = (size_t)b * 2048 + q0 + wq + mi * 16 + qd * 4 + r;
#pragma unroll
            for (int dj = 0; dj < 8; ++dj)
                out[row * 2048 + h * 128 + dj * 16 + m16] =
                    f32_to_bf16_rne(accO[mi][dj][r] * inv);
        }
}

// ---------- launch ----------
extern "C" void kernel_launch(void* const* d_in, const int* in_sizes, int n_in,
                              void* d_out, int out_size, void* d_ws, size_t ws_size,
                              hipStream_t stream) {
    const float* x     = (const float*)d_in[0];
    const float* W_qkv = (const float*)d_in[1];
    const float* W_out = (const float*)d_in[2];
    float* out = (float*)d_out;

    char* ws = (char*)d_ws;
    u16* xb   = (u16*)(ws);
    u16* Wqt  = (u16*)(ws + (16u << 20));
    u16* Wot  = (u16*)(ws + (40u << 20));
    u16* qkvb = (u16*)(ws + (48u << 20));
    u16* attn = (u16*)(ws + (96u << 20));
    u16* vtg  = (u16*)(ws + (112u << 20));

    k_cast<<<8192, 256, 0, stream>>>(x, xb);
    k_transpose_cast<<<dim3(96, 32), 256, 0, stream>>>(W_qkv, Wqt, 2048, 6144);
    k_transpose_cast<<<dim3(32, 32), 256, 0, stream>>>(W_out, Wot, 2048, 2048);
    k_gemm_bt<true><<<dim3(48, 32), 256, 0, stream>>>(xb, Wqt, qkvb, 4096, 6144, 2048);
    k_rope<<<32768, 256, 0, stream>>>(qkvb);
    k_transpose_v<<<dim3(32, 64), 256, 0, stream>>>(qkvb, vtg);
    k_flash<<<dim3(16, 32), 256, 0, stream>>>(qkvb, vtg, attn);
    k_gemm_bt<false><<<dim3(16, 32), 256, 0, stream>>>(attn, Wot, out, 4096, 2048, 2048);
}